// Round 21
// baseline (116.142 us; speedup 1.0000x reference)
//
#include <hip/hip_runtime.h>
#include <stdint.h>

// ---------------------------------------------------------------------------
// MultiDilatelocalAttention (B=4, H=W=128, C=256, heads=8, K=3, dil={2,3})
//   1) qkv = x @ Wqkv^T   (bf16 MFMA GEMM; x f32, cvt fused at fragment load;
//      R21: 64x128 tile, 32 KB LDS -> 5 blocks/CU, 20 waves/CU)
//   2) dilated 3x3 local attention (LDS-tiled, lane-pair halves)  [R11 form]
//   3) out = xo @ Wproj^T + bproj  (bf16 MFMA GEMM, fp32 out, tri-buffer)
// R21 theory: plateau band 111-114us across 5 structural variants; QKV's
// only consistently-bad counter is occupancy (28% at 48KB LDS = 3 blocks/CU).
// The measured-positive lever on this workload is block TLP via smaller LDS
// (R7). M-tile 128->64: A f32 8KB + B 8KB per buf, dbuf = 32KB -> 5
// blocks/CU; grid 3072->6144; acc 64->32 VGPR. Staging formulas identical to
// R13 (2 issues each instead of 4/2); WAITVM(4) dbuf ledger (R7-proven).
// ---------------------------------------------------------------------------

typedef __attribute__((ext_vector_type(8))) short bf16x8;
typedef __attribute__((ext_vector_type(4))) float f32x4;
typedef __attribute__((ext_vector_type(2))) float f32x2;

__device__ __forceinline__ f32x2 up2(unsigned u) {
  union { unsigned u; float f; } a, b;
  a.u = u << 16;
  b.u = u & 0xffff0000u;
  return (f32x2){a.f, b.f};
}
__device__ __forceinline__ unsigned short f2bf(float f) {
  union { float f; unsigned u; } x; x.f = f;
  unsigned r = x.u + 0x7fffu + ((x.u >> 16) & 1u);   // RNE
  return (unsigned short)(r >> 16);
}
__device__ __forceinline__ unsigned pk2bf(float a, float b) {
  return (unsigned)f2bf(a) | ((unsigned)f2bf(b) << 16);
}
// HW packed f32->bf16 RNE (same rounding as f2bf).
__device__ __forceinline__ unsigned cvtpk(float a, float b) {
  unsigned r;
  asm("v_cvt_pk_bf16_f32 %0, %1, %2" : "=v"(r) : "v"(a), "v"(b));
  return r;
}

// ------------------------------- weight cvt --------------------------------
// Both weight matrices in one launch. dst is contiguous (wqkvb|wprojb);
// elements 0..196607 come from Wqkv, the rest from Wproj (block-uniform).
__global__ __launch_bounds__(256) void cvt_w_both(
    const float* __restrict__ wqkv, const float* __restrict__ wproj,
    unsigned short* __restrict__ dst) {
  const int i = (blockIdx.x * 256 + threadIdx.x) * 8;
  const float* src = (i < 196608) ? (wqkv + i) : (wproj + (i - 196608));
  const float4* s = (const float4*)src;
  float4 a = s[0], b = s[1];
  uint4 o;
  o.x = pk2bf(a.x, a.y); o.y = pk2bf(a.z, a.w);
  o.z = pk2bf(b.x, b.y); o.w = pk2bf(b.z, b.w);
  *(uint4*)(dst + i) = o;
}

// ------------------------- sync helpers ------------------------------------
#define BARX()                                                \
  do {                                                        \
    asm volatile("s_waitcnt lgkmcnt(0)" ::: "memory");        \
    __builtin_amdgcn_s_barrier();                             \
    __builtin_amdgcn_sched_barrier(0);                        \
  } while (0)
#define WAITVM(n)                                             \
  do {                                                        \
    asm volatile("s_waitcnt vmcnt(" #n ")" ::: "memory");     \
    __builtin_amdgcn_sched_barrier(0);                        \
  } while (0)

// --------------------- QKV GEMM (R21: 64x128 tile, 32 KB LDS) --------------
// A = x (f32, staged raw via global_load_lds, cvt at fragment load),
// B = Wqkv (bf16). Tile 64x128, 4 waves as 2M x 2N of 32x64 each.
// Buf layout (ushorts): A f32 [buf*8192, +4096), B bf16 [buf*8192+4096, +4096).
__global__ __launch_bounds__(256) void gemm_qkv(
    const float* __restrict__ Af, const unsigned short* __restrict__ B,
    unsigned short* __restrict__ Cout) {
  __shared__ __align__(16) unsigned short lds[2 * 8192];   // 32 KB

  const int tid  = threadIdx.x;
  const int lane = tid & 63;
  const int wv   = tid >> 6;
  const int wr   = wv >> 1;   // M half (0..1), 32 rows each
  const int wc   = wv & 1;    // N half (0..1), 64 cols each

  // XCD-chunked bijective swizzle (gridDim.x = 6144, %8 == 0), N-major.
  const int nwg = gridDim.x;
  const int q8  = nwg >> 3;
  const int nid = (blockIdx.x & 7) * q8 + (blockIdx.x >> 3);
  const int n0  = (nid % 6) * 128;
  const int m0  = (nid / 6) * 64;

  // A f32 staging: per issue it (0..1), row = it*32 + wv*8 + (l>>3),
  // slot gran = l&7; pre-swizzled source granule (l&7)^(l>>3) [key=row&7].
  const int stg_rowA = wv * 8 + (lane >> 3);
  const int stg_kA   = ((lane & 7) ^ (lane >> 3)) * 4;   // f32 col
  const float* Ag = Af + (size_t)(m0 + stg_rowA) * 256 + stg_kA;

  // B staging: per issue it (0..1), row = it*64 + wv*16 + (l>>2), gran=l&3,
  // pre-swizzled source granule (l&3)^((l>>3)&3) [64B rows, key=(row>>1)&3].
  const int stg_rowB = wv * 16 + (lane >> 2);
  const int stg_kB   = ((lane & 3) ^ ((lane >> 3) & 3)) * 8;
  const unsigned short* Bg = B + (size_t)(n0 + stg_rowB) * 256 + stg_kB;

  f32x4 acc[2][4];
#pragma unroll
  for (int i = 0; i < 2; ++i)
#pragma unroll
    for (int j = 0; j < 4; ++j) acc[i][j] = (f32x4){0.f, 0.f, 0.f, 0.f};

  const int a_r = lane & 15;   // row within 16x16 fragment

#define QSTAGE(buf, kt)                                                        \
  do {                                                                         \
    const float* Asrc = Ag + (kt) * 32;                                        \
    const unsigned short* Bsrc = Bg + (kt) * 32;                               \
    _Pragma("unroll")                                                          \
    for (int it = 0; it < 2; ++it)                                             \
      __builtin_amdgcn_global_load_lds(                                        \
          (const __attribute__((address_space(1))) void*)(Asrc + (size_t)it * 32 * 256), \
          (__attribute__((address_space(3))) void*)&lds[(buf) * 8192 + it * 2048 + wv * 512], \
          16, 0, 0);                                                           \
    _Pragma("unroll")                                                          \
    for (int it = 0; it < 2; ++it)                                             \
      __builtin_amdgcn_global_load_lds(                                        \
          (const __attribute__((address_space(1))) void*)(Bsrc + (size_t)it * 64 * 256), \
          (__attribute__((address_space(3))) void*)&lds[(buf) * 8192 + 4096 + it * 2048 + wv * 512], \
          16, 0, 0);                                                           \
  } while (0)

// A read: granule pair {2g, 2g+1}, g = lane>>4; slot = G ^ (row&7),
// row&7 == lane&7 (fragment row bases are multiples of 16). cvt at load.
// B read: 64B rows, slot = (lane>>4) ^ ((lane>>1)&3).
#define QCOMPUTE(buf)                                                          \
  do {                                                                         \
    const int gswB = (((lane >> 4) ^ ((lane >> 1) & 3))) * 8;                  \
    const int sA0  = ((2 * (lane >> 4)) ^ (lane & 7)) * 4;                     \
    const int sA1  = sA0 ^ 4;                                                  \
    const float* Afl = (const float*)lds;                                      \
    bf16x8 af[2], bfr[4];                                                      \
    _Pragma("unroll")                                                          \
    for (int mi = 0; mi < 2; ++mi) {                                           \
      const int rb = (buf) * 4096 + (wr * 32 + mi * 16 + a_r) * 32;            \
      f32x4 lo = *(const f32x4*)&Afl[rb + sA0];                                \
      f32x4 hi = *(const f32x4*)&Afl[rb + sA1];                                \
      uint4 pk;                                                                \
      pk.x = cvtpk(lo.x, lo.y); pk.y = cvtpk(lo.z, lo.w);                      \
      pk.z = cvtpk(hi.x, hi.y); pk.w = cvtpk(hi.z, hi.w);                      \
      af[mi] = *(bf16x8*)&pk;                                                  \
    }                                                                          \
    _Pragma("unroll")                                                          \
    for (int ni = 0; ni < 4; ++ni)                                             \
      bfr[ni] = *(const bf16x8*)&lds[(buf) * 8192 + 4096 + (wc * 64 + ni * 16 + a_r) * 32 + gswB]; \
    _Pragma("unroll")                                                          \
    for (int mi = 0; mi < 2; ++mi)                                             \
      _Pragma("unroll")                                                        \
      for (int ni = 0; ni < 4; ++ni)                                           \
        acc[mi][ni] = __builtin_amdgcn_mfma_f32_16x16x32_bf16(                 \
            af[mi], bfr[ni], acc[mi][ni], 0, 0, 0);                            \
  } while (0)

  // Double buffer, 4 vm-ops/STAGE, WAITVM(4) ledger (R7-proven).
  QSTAGE(0, 0);
  QSTAGE(1, 1);
  WAITVM(4);  BARX();
  QCOMPUTE(0); BARX();
  QSTAGE(0, 2); WAITVM(4); BARX();
  QCOMPUTE(1); BARX();
  QSTAGE(1, 3); WAITVM(4); BARX();
  QCOMPUTE(0); BARX();
  QSTAGE(0, 4); WAITVM(4); BARX();
  QCOMPUTE(1); BARX();
  QSTAGE(1, 5); WAITVM(4); BARX();
  QCOMPUTE(0); BARX();
  QSTAGE(0, 6); WAITVM(4); BARX();
  QCOMPUTE(1); BARX();
  QSTAGE(1, 7); WAITVM(4); BARX();
  QCOMPUTE(0); BARX();
  WAITVM(0);   BARX();
  QCOMPUTE(1); BARX();   // LDS about to be reused by epilogue

  // ---- epilogue: 64 rows x (128+8) bf16, stride 272 B; coalesced stores ----
  unsigned short* eb = &lds[0];
#pragma unroll
  for (int ni = 0; ni < 4; ++ni)
#pragma unroll
    for (int mi = 0; mi < 2; ++mi)
#pragma unroll
      for (int r = 0; r < 4; ++r)
        eb[(wr * 32 + mi * 16 + (lane >> 4) * 4 + r) * 136 +
           wc * 64 + ni * 16 + a_r] = f2bf(acc[mi][ni][r]);
  BARX();   // lgkmcnt(0) drain inside: publishes ds_writes to all waves
#pragma unroll
  for (int p = 0; p < 4; ++p) {
    const int idx = p * 256 + tid;
    const int row = idx >> 4;          // 0..63
    const int seg = idx & 15;
    uint4 v = *(const uint4*)&eb[row * 136 + seg * 8];
    *(uint4*)&Cout[(size_t)(m0 + row) * 768 + n0 + seg * 8] = v;
  }
#undef QSTAGE
#undef QCOMPUTE
}

// --------------------- proj GEMM (R13/R20 form, tri-buffer) -----------------
// A: xo (bf16), B: Wproj (bf16), C: f32 + bias. 128x128 tile, tri-buffer,
// one barrier per K-tile, WAITVM(4).
__global__ __launch_bounds__(256) void gemm_proj(
    const unsigned short* __restrict__ A, const unsigned short* __restrict__ B,
    float* __restrict__ C, const float* __restrict__ bias, int N, int NT) {
  __shared__ __align__(16) unsigned short lds[24576];   // 48 KB

  const int tid  = threadIdx.x;
  const int lane = tid & 63;
  const int wv   = tid >> 6;
  const int wr   = wv >> 1;   // wave row (0..1)
  const int wc   = wv & 1;    // wave col (0..1)

  const int nwg = gridDim.x;
  const int q8  = nwg >> 3;
  const int nid = (blockIdx.x & 7) * q8 + (blockIdx.x >> 3);
  const int n0  = (nid % NT) * 128;
  const int m0  = (nid / NT) * 128;

  const int stg_row = wv * 16 + (lane >> 2);
  const int stg_k   = ((lane & 3) ^ ((lane >> 3) & 3)) * 8;
  const unsigned short* Ag = A + (size_t)(m0 + stg_row) * 256 + stg_k;
  const unsigned short* Bg = B + (size_t)(n0 + stg_row) * 256 + stg_k;

  f32x4 acc[4][4];
#pragma unroll
  for (int i = 0; i < 4; ++i)
#pragma unroll
    for (int j = 0; j < 4; ++j) acc[i][j] = (f32x4){0.f, 0.f, 0.f, 0.f};

  const int a_r = lane & 15;

#define PSTAGE(buf, kt)                                                        \
  do {                                                                         \
    const unsigned short* Asrc = Ag + (kt) * 32;                               \
    const unsigned short* Bsrc = Bg + (kt) * 32;                               \
    _Pragma("unroll")                                                          \
    for (int it = 0; it < 2; ++it) {                                           \
      __builtin_amdgcn_global_load_lds(                                        \
          (const __attribute__((address_space(1))) void*)(Asrc + (size_t)it * 64 * 256), \
          (__attribute__((address_space(3))) void*)&lds[(buf) * 8192 + it * 2048 + wv * 512], \
          16, 0, 0);                                                           \
      __builtin_amdgcn_global_load_lds(                                        \
          (const __attribute__((address_space(1))) void*)(Bsrc + (size_t)it * 64 * 256), \
          (__attribute__((address_space(3))) void*)&lds[(buf) * 8192 + 4096 + it * 2048 + wv * 512], \
          16, 0, 0);                                                           \
    }                                                                          \
  } while (0)

#define PCOMPUTE(buf)                                                          \
  do {                                                                         \
    const int gsw = (((lane >> 4) ^ ((lane >> 1) & 3))) * 8;                   \
    bf16x8 af[4], bfr[4];                                                      \
    _Pragma("unroll")                                                          \
    for (int mi = 0; mi < 4; ++mi)                                             \
      af[mi] = *(const bf16x8*)&lds[(buf) * 8192 + (wr * 64 + mi * 16 + a_r) * 32 + gsw]; \
    _Pragma("unroll")                                                          \
    for (int ni = 0; ni < 4; ++ni)                                             \
      bfr[ni] = *(const bf16x8*)&lds[(buf) * 8192 + 4096 + (wc * 64 + ni * 16 + a_r) * 32 + gsw]; \
    _Pragma("unroll")                                                          \
    for (int mi = 0; mi < 4; ++mi)                                             \
      _Pragma("unroll")                                                        \
      for (int ni = 0; ni < 4; ++ni)                                           \
        acc[mi][ni] = __builtin_amdgcn_mfma_f32_16x16x32_bf16(                 \
            af[mi], bfr[ni], acc[mi][ni], 0, 0, 0);                            \
  } while (0)

  PSTAGE(0, 0);
  PSTAGE(1, 1);
  WAITVM(4); BARX();
  PCOMPUTE(0); PSTAGE(2, 2); WAITVM(4); BARX();
  PCOMPUTE(1); PSTAGE(0, 3); WAITVM(4); BARX();
  PCOMPUTE(2); PSTAGE(1, 4); WAITVM(4); BARX();
  PCOMPUTE(0); PSTAGE(2, 5); WAITVM(4); BARX();
  PCOMPUTE(1); PSTAGE(0, 6); WAITVM(4); BARX();
  PCOMPUTE(2); PSTAGE(1, 7); WAITVM(4); BARX();
  PCOMPUTE(0); WAITVM(0); BARX();
  PCOMPUTE(1); BARX();   // LDS about to be reused by epilogue

  // f32 epilogue: two 64-row halves of (128+4)-f32-stride rows
  float* ef = (float*)&lds[0];
  float bv[4];
#pragma unroll
  for (int ni = 0; ni < 4; ++ni) bv[ni] = bias[n0 + wc * 64 + ni * 16 + a_r];
#pragma unroll
  for (int half = 0; half < 2; ++half) {
    if (wr == half) {
      const int rb = (lane >> 4) * 4;
#pragma unroll
      for (int ni = 0; ni < 4; ++ni)
#pragma unroll
        for (int mi = 0; mi < 4; ++mi)
#pragma unroll
          for (int r = 0; r < 4; ++r)
            ef[(rb + mi * 16 + r) * 132 + wc * 64 + ni * 16 + a_r] =
                acc[mi][ni][r] + bv[ni];
    }
    BARX();
#pragma unroll
    for (int p = 0; p < 8; ++p) {
      const int idx = p * 256 + tid;
      const int row = idx >> 5;
      const int seg = idx & 31;
      f32x4 v = *(const f32x4*)&ef[row * 132 + seg * 4];
      *(f32x4*)&C[(size_t)(m0 + half * 64 + row) * N + n0 + seg * 4] = v;
    }
    BARX();
  }
#undef PSTAGE
#undef PCOMPUTE
}

// --------------------------- dilated local attention -----------------------
// One block = 16x16 px tile x one combo, 512 threads: thread = (pixel, half),
// half = t&1 owns 16 channels (planes 2*half, 2*half+1). ONE 4-plane LDS
// buffer (31KB) reused K-then-V; OOB pixels zero-filled. Score = half-dot +
// one shfl_xor(1) per tap (lane pair shares a pixel). Softmax identical in
// both lanes. Layout [plane 0..3][485 px][16B]; tap (i,j) of pixel (ph,pw):
// lp = (ph+i*d)*22 + (pw+j*d); tile origin (h0-d, w0-d).
__global__ __launch_bounds__(512) void attn_kernel(
    const unsigned short* __restrict__ qkv, unsigned short* __restrict__ xo) {
  __shared__ __align__(16) unsigned short lds[4 * 485 * 8];   // 31040 B

  const int nwg = gridDim.x;            // 2048, %8 == 0
  const int q8  = nwg >> 3;
  const int nid = (blockIdx.x & 7) * q8 + (blockIdx.x >> 3);
  const int combo = nid & 7;
  const int tw    = (nid >> 3) & 7;
  const int th    = (nid >> 6) & 7;
  const int b     = nid >> 9;
  const int d     = (combo >> 2) ? 3 : 2;     // DILATIONS = (2, 3)
  const int choff = combo * 32;
  const int h0 = th * 16, w0 = tw * 16;
  const int t = threadIdx.x;

  const int splane = t & 3;
  const int t4     = t >> 2;
  const int schoff = choff + splane * 8;

  // ---- stage K (zero-filled OOB) ----
#pragma unroll
  for (int it = 0; it < 4; ++it) {
    const int px = it * 128 + t4;
    const int r = px / 22, c = px % 22;     // magic-mul
    const int gh = h0 - d + r;
    const int gw = w0 - d + c;
    const bool ok = ((unsigned)gh < 128u) && ((unsigned)gw < 128u);
    const int hcl = min(max(gh, 0), 127);
    const int wcl = min(max(gw, 0), 127);
    const int gp = (((b << 7) | hcl) << 7) | wcl;
    uint4 u = *(const uint4*)(qkv + (size_t)gp * 768 + 256 + schoff);
    if (!ok) u = make_uint4(0u, 0u, 0u, 0u);
    if (it < 3 || t < 400) *(uint4*)&lds[(splane * 485 + px) * 8] = u;
  }

  // ---- q (16 ch for this half), scale folded in ----
  const int half = t & 1;
  const int ph = (t >> 1) >> 4, pw = (t >> 1) & 15;
  const int gp0 = (((b << 7) | (h0 + ph)) << 7) | (w0 + pw);
  const unsigned short* qp = qkv + (size_t)gp0 * 768 + choff + half * 16;
  uint4 uq0 = *(const uint4*)qp;
  uint4 uq1 = *(const uint4*)(qp + 8);
  f32x2 q2[8];
  {
    const f32x2 s2 = {0.17677669529663687f, 0.17677669529663687f};  // 32^-0.5
    q2[0] = up2(uq0.x) * s2; q2[1] = up2(uq0.y) * s2;
    q2[2] = up2(uq0.z) * s2; q2[3] = up2(uq0.w) * s2;
    q2[4] = up2(uq1.x) * s2; q2[5] = up2(uq1.y) * s2;
    q2[6] = up2(uq1.z) * s2; q2[7] = up2(uq1.w) * s2;
  }
  __syncthreads();

  // ---- scores: 9 taps, 2 planes each (this half), branch-free ----
  const int p0 = 2 * half, p1 = 2 * half + 1;
  float sc[9];
#pragma unroll
  for (int i = 0; i < 3; ++i) {
#pragma unroll
    for (int j = 0; j < 3; ++j) {
      const int lp = (ph + i * d) * 22 + (pw + j * d);
      const uint4 k0 = *(const uint4*)&lds[(p0 * 485 + lp) * 8];
      const uint4 k1 = *(const uint4*)&lds[(p1 * 485 + lp) * 8];
      f32x2 a = q2[0] * up2(k0.x);
      a += q2[1] * up2(k0.y); a += q2[2] * up2(k0.z); a += q2[3] * up2(k0.w);
      a += q2[4] * up2(k1.x); a += q2[5] * up2(k1.y);
      a += q2[6] * up2(k1.z); a += q2[7] * up2(k1.w);
      sc[i * 3 + j] = a.x + a.y;        // half-dot
    }
  }
#pragma unroll
  for (int k = 0; k < 9; ++k) sc[k] += __shfl_xor(sc[k], 1);

  // ---- softmax over 9 (identical in both halves) ----
  float mx = sc[0];
#pragma unroll
  for (int k = 1; k < 9; ++k) mx = fmaxf(mx, sc[k]);
  float sum = 0.f;
#pragma unroll
  for (int k = 0; k < 9; ++k) { sc[k] = __expf(sc[k] - mx); sum += sc[k]; }
  const float inv = 1.f / sum;

  // ---- all waves done reading K; overwrite buffer with V ----
  __syncthreads();
#pragma unroll
  for (int it = 0; it < 4; ++it) {
    const int px = it * 128 + t4;
    const int r = px / 22, c = px % 22;
    const int gh = h0 - d + r;
    const int gw = w0 - d + c;
    const bool ok = ((unsigned)gh < 128u) && ((unsigned)gw < 128u);
    const int hcl = min(max(gh, 0), 127);
    const int wcl = min(max(gw, 0), 127);
    const int gp = (((b << 7) | hcl) << 7) | wcl;
    uint4 u = *(const uint4*)(qkv + (size_t)gp * 768 + 512 + schoff);
    if (!ok) u = make_uint4(0u, 0u, 0u, 0u);
    if (it < 3 || t < 400) *(uint4*)&lds[(splane * 485 + px) * 8] = u;
  }
  __syncthreads();

  // ---- weighted V accumulate (this half's 16 ch), branch-free ----
  f32x2 o2[8];
#pragma unroll
  for (int k = 0; k < 8; ++k) o2[k] = (f32x2){0.f, 0.f};
#pragma unroll
  for (int i = 0; i < 3; ++i) {
#pragma unroll
    for (int j = 0; j < 3; ++j) {
      const int lp = (ph + i * d) * 22 + (pw + j * d);
      const uint4 v0 = *(const uint4*)&lds[(p0 * 485 + lp) * 8];
      const uint4 v1 = *(const uint4*)&lds[(p1 * 485 + lp) * 8];
      const float wv = sc[i * 3 + j] * inv;
      const f32x2 w2 = {wv, wv};
      o2[0] += w2 * up2(v0.x); o2[1] += w2 * up2(v0.y);
      o2[2] += w2 * up2(v0.z); o2[3] += w2 * up2(v0.w);
      o2[4] += w2 * up2(v1.x); o2[5] += w2 * up2(v1.y);
      o2[6] += w2 * up2(v1.z); o2[7] += w2 * up2(v1.w);
    }
  }

  // ---- store 16 ch bf16 ----
  unsigned short* op = xo + (size_t)gp0 * 256 + choff + half * 16;
  uint4 s0, s1;
  s0.x = pk2bf(o2[0].x, o2[0].y); s0.y = pk2bf(o2[1].x, o2[1].y);
  s0.z = pk2bf(o2[2].x, o2[2].y); s0.w = pk2bf(o2[3].x, o2[3].y);
  s1.x = pk2bf(o2[4].x, o2[4].y); s1.y = pk2bf(o2[5].x, o2[5].y);
  s1.z = pk2bf(o2[6].x, o2[6].y); s1.w = pk2bf(o2[7].x, o2[7].y);
  *(uint4*)op       = s0;
  *(uint4*)(op + 8) = s1;
}

// ---------------------------------------------------------------------------
extern "C" void kernel_launch(void* const* d_in, const int* in_sizes, int n_in,
                              void* d_out, int out_size, void* d_ws, size_t ws_size,
                              hipStream_t stream) {
  const float* x     = (const float*)d_in[0];
  const float* Wqkv  = (const float*)d_in[1];
  const float* Wproj = (const float*)d_in[2];
  const float* bproj = (const float*)d_in[3];

  const int M = 4 * 128 * 128;   // 65536 pixels
  const int C = 256;

  // workspace layout (bf16 ushorts): qkv | xo | Wqkv_b | Wproj_b (~130 MB)
  unsigned short* qkvb   = (unsigned short*)d_ws;
  unsigned short* xob    = qkvb + (size_t)M * 3 * C;
  unsigned short* wqkvb  = xob + (size_t)M * C;

  // both weight matrices: (3*C*C + C*C)/8 / 256 = 128 blocks, dsts contiguous
  cvt_w_both<<<128, 256, 0, stream>>>(Wqkv, Wproj, wqkvb);

  // QKV: 64x128 tiles -> (M/64) x 6 = 6144 blocks, 256 threads
  gemm_qkv<<<(M / 64) * 6, 256, 0, stream>>>(x, wqkvb, qkvb);

  // 4 batches x 8x8 tiles x 8 combos = 2048 blocks, 512 threads (px x half)
  attn_kernel<<<2048, 512, 0, stream>>>(qkvb, xob);

  gemm_proj<<<(M / 128) * (C / 128), 256, 0, stream>>>(
      xob, wqkvb + (size_t)3 * C * C, (float*)d_out, bproj, C, C / 128);
}

// Round 22
// 107.927 us; speedup vs baseline: 1.0761x; 1.0761x over previous
//
#include <hip/hip_runtime.h>
#include <stdint.h>

// ---------------------------------------------------------------------------
// MultiDilatelocalAttention (B=4, H=W=128, C=256, heads=8, K=3, dil={2,3})
//   1) qkv = x @ Wqkv^T   (bf16 MFMA GEMM; x f32, cvt fused at fragment load)
//   2) dilated 3x3 local attention (LDS-tiled, lane-pair halves)
//   3) out = xo @ Wproj^T + bproj  (bf16 MFMA GEMM, fp32 out, tri-buffer)
// R22: restore best-measured configuration (R13 = 110.7us; band 111-114).
// Plateau evidence: 8 structural variants (BK 64/32, dbuf/tri-buf, barrier
// 2x/1x per K-tile, cvt produce/consume, tile 128x128/64x128/128x256, NT,
// occupancy 28->38%) all land 111-116us. Each kernel ~2x its HBM floor
// (total floor ~60us); counters show exposed latency, not a saturated pipe.
// Remaining lever = co-designed 8-phase pipeline (T2+T3+T4+T5), a new sync
// template requiring its own race-screen campaign - out of incremental scope.
// ---------------------------------------------------------------------------

typedef __attribute__((ext_vector_type(8))) short bf16x8;
typedef __attribute__((ext_vector_type(4))) float f32x4;
typedef __attribute__((ext_vector_type(2))) float f32x2;

__device__ __forceinline__ f32x2 up2(unsigned u) {
  union { unsigned u; float f; } a, b;
  a.u = u << 16;
  b.u = u & 0xffff0000u;
  return (f32x2){a.f, b.f};
}
__device__ __forceinline__ unsigned short f2bf(float f) {
  union { float f; unsigned u; } x; x.f = f;
  unsigned r = x.u + 0x7fffu + ((x.u >> 16) & 1u);   // RNE
  return (unsigned short)(r >> 16);
}
__device__ __forceinline__ unsigned pk2bf(float a, float b) {
  return (unsigned)f2bf(a) | ((unsigned)f2bf(b) << 16);
}
// HW packed f32->bf16 RNE (same rounding as f2bf).
__device__ __forceinline__ unsigned cvtpk(float a, float b) {
  unsigned r;
  asm("v_cvt_pk_bf16_f32 %0, %1, %2" : "=v"(r) : "v"(a), "v"(b));
  return r;
}

// ------------------------------- weight cvt --------------------------------
// Both weight matrices in one launch. dst is contiguous (wqkvb|wprojb);
// elements 0..196607 come from Wqkv, the rest from Wproj (block-uniform).
__global__ __launch_bounds__(256) void cvt_w_both(
    const float* __restrict__ wqkv, const float* __restrict__ wproj,
    unsigned short* __restrict__ dst) {
  const int i = (blockIdx.x * 256 + threadIdx.x) * 8;
  const float* src = (i < 196608) ? (wqkv + i) : (wproj + (i - 196608));
  const float4* s = (const float4*)src;
  float4 a = s[0], b = s[1];
  uint4 o;
  o.x = pk2bf(a.x, a.y); o.y = pk2bf(a.z, a.w);
  o.z = pk2bf(b.x, b.y); o.w = pk2bf(b.z, b.w);
  *(uint4*)(dst + i) = o;
}

// ------------------------- GEMM: C = A @ B^T -------------------------------
#define BARX()                                                \
  do {                                                        \
    asm volatile("s_waitcnt lgkmcnt(0)" ::: "memory");        \
    __builtin_amdgcn_s_barrier();                             \
    __builtin_amdgcn_sched_barrier(0);                        \
  } while (0)
#define WAITVM(n)                                             \
  do {                                                        \
    asm volatile("s_waitcnt vmcnt(" #n ")" ::: "memory");     \
    __builtin_amdgcn_sched_barrier(0);                        \
  } while (0)

// AF32=1: A is f32 (x), staged raw, converted at fragment load. Double
// buffer: buf in {0,1}, 24 KB each (A f32 16 KB + B bf16 8 KB).
// AF32=0: A is bf16, tri-buffer (buf in {0,1,2}, 16 KB each), one barrier
// per K-tile.
template <int OUTF32, int AF32>
__global__ __launch_bounds__(256) void gemm_bt(
    const void* __restrict__ Ap, const unsigned short* __restrict__ B,
    void* __restrict__ Cout, const float* __restrict__ bias,
    int N, int NT) {
  __shared__ __align__(16) unsigned short lds[24576];   // 48 KB both modes

  const int tid  = threadIdx.x;
  const int lane = tid & 63;
  const int wv   = tid >> 6;
  const int wr   = wv >> 1;   // wave row (0..1)
  const int wc   = wv & 1;    // wave col (0..1)

  // XCD-chunked bijective swizzle (gridDim.x % 8 == 0), N-major tile order.
  const int nwg = gridDim.x;
  const int q8  = nwg >> 3;
  const int nid = (blockIdx.x & 7) * q8 + (blockIdx.x >> 3);
  const int n0  = (nid % NT) * 128;
  const int m0  = (nid / NT) * 128;

  const float* Af          = (const float*)Ap;
  const unsigned short* Ab = (const unsigned short*)Ap;

  // B staging (and bf16-A staging): row = it*64 + wv*16 + (l>>2), gran=l&3,
  // pre-swizzled source granule (l&3)^((l>>3)&3)  [64B rows, key=(row>>1)&3]
  const int stg_rowB = wv * 16 + (lane >> 2);
  const int stg_kB   = ((lane & 3) ^ ((lane >> 3) & 3)) * 8;
  const unsigned short* Bg   = B  + (size_t)(n0 + stg_rowB) * 256 + stg_kB;
  const unsigned short* Ag16 = Ab + (size_t)(m0 + stg_rowB) * 256 + stg_kB;

  // f32-A staging: per issue, row = it*32 + wv*8 + (l>>3), slot gran = l&7;
  // pre-swizzled source granule (l&7)^(l>>3)  [128 B rows, key=row&7]
  const int stg_rowA32 = wv * 8 + (lane >> 3);
  const int stg_kA32   = ((lane & 7) ^ (lane >> 3)) * 4;   // f32 col
  const float* Ag32 = Af + (size_t)(m0 + stg_rowA32) * 256 + stg_kA32;

  f32x4 acc[4][4];
#pragma unroll
  for (int i = 0; i < 4; ++i)
#pragma unroll
    for (int j = 0; j < 4; ++j) acc[i][j] = (f32x4){0.f, 0.f, 0.f, 0.f};

  const int a_r = lane & 15;   // row within 16x16 fragment

#define STAGE16(buf, kt)                                                       \
  do {                                                                         \
    const unsigned short* Asrc = Ag16 + (kt) * 32;                             \
    const unsigned short* Bsrc = Bg + (kt) * 32;                               \
    _Pragma("unroll")                                                          \
    for (int it = 0; it < 2; ++it) {                                           \
      __builtin_amdgcn_global_load_lds(                                        \
          (const __attribute__((address_space(1))) void*)(Asrc + (size_t)it * 64 * 256), \
          (__attribute__((address_space(3))) void*)&lds[(buf) * 8192 + it * 2048 + wv * 512], \
          16, 0, 0);                                                           \
      __builtin_amdgcn_global_load_lds(                                        \
          (const __attribute__((address_space(1))) void*)(Bsrc + (size_t)it * 64 * 256), \
          (__attribute__((address_space(3))) void*)&lds[(buf) * 8192 + 4096 + it * 2048 + wv * 512], \
          16, 0, 0);                                                           \
    }                                                                          \
  } while (0)

#define COMPUTE16(buf)                                                         \
  do {                                                                         \
    const int gsw = (((lane >> 4) ^ ((lane >> 1) & 3))) * 8;                   \
    bf16x8 af[4], bfr[4];                                                      \
    _Pragma("unroll")                                                          \
    for (int mi = 0; mi < 4; ++mi)                                             \
      af[mi] = *(const bf16x8*)&lds[(buf) * 8192 + (wr * 64 + mi * 16 + a_r) * 32 + gsw]; \
    _Pragma("unroll")                                                          \
    for (int ni = 0; ni < 4; ++ni)                                             \
      bfr[ni] = *(const bf16x8*)&lds[(buf) * 8192 + 4096 + (wc * 64 + ni * 16 + a_r) * 32 + gsw]; \
    _Pragma("unroll")                                                          \
    for (int mi = 0; mi < 4; ++mi)                                             \
      _Pragma("unroll")                                                        \
      for (int ni = 0; ni < 4; ++ni)                                           \
        acc[mi][ni] = __builtin_amdgcn_mfma_f32_16x16x32_bf16(                 \
            af[mi], bfr[ni], acc[mi][ni], 0, 0, 0);                            \
  } while (0)

// f32-A: A region [buf*12288, +8192) ushorts (16 KB f32), B at +8192 (8 KB).
#define STAGE32(buf, kt)                                                       \
  do {                                                                         \
    const float* Asrc = Ag32 + (kt) * 32;                                      \
    const unsigned short* Bsrc = Bg + (kt) * 32;                               \
    _Pragma("unroll")                                                          \
    for (int it = 0; it < 4; ++it)                                             \
      __builtin_amdgcn_global_load_lds(                                        \
          (const __attribute__((address_space(1))) void*)(Asrc + (size_t)it * 32 * 256), \
          (__attribute__((address_space(3))) void*)&lds[(buf) * 12288 + it * 2048 + wv * 512], \
          16, 0, 0);                                                           \
    _Pragma("unroll")                                                          \
    for (int it = 0; it < 2; ++it)                                             \
      __builtin_amdgcn_global_load_lds(                                        \
          (const __attribute__((address_space(1))) void*)(Bsrc + (size_t)it * 64 * 256), \
          (__attribute__((address_space(3))) void*)&lds[(buf) * 12288 + 8192 + it * 2048 + wv * 512], \
          16, 0, 0);                                                           \
  } while (0)

// A read: global granule pair {2g, 2g+1}, g = lane>>4; slot = G ^ (row&7),
// row&7 == lane&7 (fragment row bases are multiples of 16). Pair slots are
// s and s^1.
#define COMPUTE32(buf)                                                         \
  do {                                                                         \
    const int gswB = (((lane >> 4) ^ ((lane >> 1) & 3))) * 8;                  \
    const int sA0  = ((2 * (lane >> 4)) ^ (lane & 7)) * 4;                     \
    const int sA1  = (((2 * (lane >> 4)) ^ (lane & 7)) ^ 1) * 4;               \
    const float* Afl = (const float*)lds;                                      \
    bf16x8 af[4], bfr[4];                                                      \
    _Pragma("unroll")                                                          \
    for (int mi = 0; mi < 4; ++mi) {                                           \
      const int rb = (buf) * 6144 + (wr * 64 + mi * 16 + a_r) * 32;            \
      f32x4 lo = *(const f32x4*)&Afl[rb + sA0];                                \
      f32x4 hi = *(const f32x4*)&Afl[rb + sA1];                                \
      uint4 pk;                                                                \
      pk.x = cvtpk(lo.x, lo.y); pk.y = cvtpk(lo.z, lo.w);                      \
      pk.z = cvtpk(hi.x, hi.y); pk.w = cvtpk(hi.z, hi.w);                      \
      af[mi] = *(bf16x8*)&pk;                                                  \
    }                                                                          \
    _Pragma("unroll")                                                          \
    for (int ni = 0; ni < 4; ++ni)                                             \
      bfr[ni] = *(const bf16x8*)&lds[(buf) * 12288 + 8192 + (wc * 64 + ni * 16 + a_r) * 32 + gswB]; \
    _Pragma("unroll")                                                          \
    for (int mi = 0; mi < 4; ++mi)                                             \
      _Pragma("unroll")                                                        \
      for (int ni = 0; ni < 4; ++ni)                                           \
        acc[mi][ni] = __builtin_amdgcn_mfma_f32_16x16x32_bf16(                 \
            af[mi], bfr[ni], acc[mi][ni], 0, 0, 0);                            \
  } while (0)

  if constexpr (AF32) {
    // Double buffer, R7-proven ledger, 6 loads/STAGE (4 A f32 + 2 B).
    STAGE32(0, 0);
    STAGE32(1, 1);
    WAITVM(6);  BARX();
    COMPUTE32(0); BARX();
    STAGE32(0, 2); WAITVM(6); BARX();
    COMPUTE32(1); BARX();
    STAGE32(1, 3); WAITVM(6); BARX();
    COMPUTE32(0); BARX();
    STAGE32(0, 4); WAITVM(6); BARX();
    COMPUTE32(1); BARX();
    STAGE32(1, 5); WAITVM(6); BARX();
    COMPUTE32(0); BARX();
    STAGE32(0, 6); WAITVM(6); BARX();
    COMPUTE32(1); BARX();
    STAGE32(1, 7); WAITVM(6); BARX();
    COMPUTE32(0); BARX();
    WAITVM(0);   BARX();
    COMPUTE32(1); BARX();   // LDS about to be reused by epilogue
  } else {
    // Tri-buffer, one barrier per K-tile, 4 gload_lds/STAGE.
    STAGE16(0, 0);
    STAGE16(1, 1);
    WAITVM(4); BARX();
    COMPUTE16(0); STAGE16(2, 2); WAITVM(4); BARX();
    COMPUTE16(1); STAGE16(0, 3); WAITVM(4); BARX();
    COMPUTE16(2); STAGE16(1, 4); WAITVM(4); BARX();
    COMPUTE16(0); STAGE16(2, 5); WAITVM(4); BARX();
    COMPUTE16(1); STAGE16(0, 6); WAITVM(4); BARX();
    COMPUTE16(2); STAGE16(1, 7); WAITVM(4); BARX();
    COMPUTE16(0); WAITVM(0); BARX();
    COMPUTE16(1); BARX();   // LDS about to be reused by epilogue
  }

  // ------------------- LDS-staged coalesced epilogue -------------------
  const int cl = wc * 64 + a_r;              // local col base
  const int rl = wr * 64 + (lane >> 4) * 4;  // local row base
  if (!OUTF32) {
    // 128 rows x (128+8) bf16 = 17408 ushorts (16B-aligned rows, bank spread)
    unsigned short* eb = &lds[0];
#pragma unroll
    for (int ni = 0; ni < 4; ++ni)
#pragma unroll
      for (int mi = 0; mi < 4; ++mi)
#pragma unroll
        for (int r = 0; r < 4; ++r)
          eb[(rl + mi * 16 + r) * 136 + cl + ni * 16] = f2bf(acc[mi][ni][r]);
    BARX();   // lgkmcnt(0) drain inside: publishes ds_writes to all waves
    unsigned short* C = (unsigned short*)Cout;
#pragma unroll
    for (int p = 0; p < 8; ++p) {
      const int idx = p * 256 + tid;
      const int row = idx >> 4;
      const int seg = idx & 15;
      uint4 v = *(const uint4*)&eb[row * 136 + seg * 8];
      *(uint4*)&C[(size_t)(m0 + row) * N + n0 + seg * 8] = v;
    }
  } else {
    // f32: two 64-row halves of (128+4)-f32-stride rows (33792 B each)
    float* ef = (float*)&lds[0];
    float* C = (float*)Cout;
    float bv[4];
#pragma unroll
    for (int ni = 0; ni < 4; ++ni) bv[ni] = bias[n0 + wc * 64 + ni * 16 + a_r];
#pragma unroll
    for (int half = 0; half < 2; ++half) {
      if (wr == half) {
        const int rb = (lane >> 4) * 4;   // local row within the half
#pragma unroll
        for (int ni = 0; ni < 4; ++ni)
#pragma unroll
          for (int mi = 0; mi < 4; ++mi)
#pragma unroll
            for (int r = 0; r < 4; ++r)
              ef[(rb + mi * 16 + r) * 132 + wc * 64 + ni * 16 + a_r] =
                  acc[mi][ni][r] + bv[ni];
      }
      BARX();   // lgkmcnt(0) drain inside
#pragma unroll
      for (int p = 0; p < 8; ++p) {
        const int idx = p * 256 + tid;
        const int row = idx >> 5;
        const int seg = idx & 31;
        f32x4 v = *(const f32x4*)&ef[row * 132 + seg * 4];
        *(f32x4*)&C[(size_t)(m0 + half * 64 + row) * N + n0 + seg * 4] = v;
      }
      BARX();
    }
  }
#undef STAGE16
#undef COMPUTE16
#undef STAGE32
#undef COMPUTE32
}

// --------------------------- dilated local attention -----------------------
// One block = 16x16 px tile x one combo, 512 threads: thread = (pixel, half),
// half = t&1 owns 16 channels (planes 2*half, 2*half+1). ONE 4-plane LDS
// buffer (31KB) reused K-then-V; OOB pixels zero-filled. Score = half-dot +
// one shfl_xor(1) per tap (lane pair shares a pixel). Softmax identical in
// both lanes. Layout [plane 0..3][485 px][16B]; tap (i,j) of pixel (ph,pw):
// lp = (ph+i*d)*22 + (pw+j*d); tile origin (h0-d, w0-d).
__global__ __launch_bounds__(512) void attn_kernel(
    const unsigned short* __restrict__ qkv, unsigned short* __restrict__ xo) {
  __shared__ __align__(16) unsigned short lds[4 * 485 * 8];   // 31040 B

  const int nwg = gridDim.x;            // 2048, %8 == 0
  const int q8  = nwg >> 3;
  const int nid = (blockIdx.x & 7) * q8 + (blockIdx.x >> 3);
  const int combo = nid & 7;
  const int tw    = (nid >> 3) & 7;
  const int th    = (nid >> 6) & 7;
  const int b     = nid >> 9;
  const int d     = (combo >> 2) ? 3 : 2;     // DILATIONS = (2, 3)
  const int choff = combo * 32;
  const int h0 = th * 16, w0 = tw * 16;
  const int t = threadIdx.x;

  // staging geometry (K and V): plane = t&3, px = it*128 + (t>>2), it<4.
  // it<3 always live; it==3 live iff t<400 (px<484). 4 consecutive lanes
  // fetch one contiguous 64B global segment.
  const int splane = t & 3;
  const int t4     = t >> 2;
  const int schoff = choff + splane * 8;

  // ---- stage K (zero-filled OOB) ----
#pragma unroll
  for (int it = 0; it < 4; ++it) {
    const int px = it * 128 + t4;
    const int r = px / 22, c = px % 22;     // magic-mul
    const int gh = h0 - d + r;
    const int gw = w0 - d + c;
    const bool ok = ((unsigned)gh < 128u) && ((unsigned)gw < 128u);
    const int hcl = min(max(gh, 0), 127);
    const int wcl = min(max(gw, 0), 127);
    const int gp = (((b << 7) | hcl) << 7) | wcl;
    uint4 u = *(const uint4*)(qkv + (size_t)gp * 768 + 256 + schoff);
    if (!ok) u = make_uint4(0u, 0u, 0u, 0u);
    if (it < 3 || t < 400) *(uint4*)&lds[(splane * 485 + px) * 8] = u;
  }

  // ---- q (16 ch for this half), scale folded in ----
  const int half = t & 1;
  const int ph = (t >> 1) >> 4, pw = (t >> 1) & 15;
  const int gp0 = (((b << 7) | (h0 + ph)) << 7) | (w0 + pw);
  const unsigned short* qp = qkv + (size_t)gp0 * 768 + choff + half * 16;
  uint4 uq0 = *(const uint4*)qp;
  uint4 uq1 = *(const uint4*)(qp + 8);
  f32x2 q2[8];
  {
    const f32x2 s2 = {0.17677669529663687f, 0.17677669529663687f};  // 32^-0.5
    q2[0] = up2(uq0.x) * s2; q2[1] = up2(uq0.y) * s2;
    q2[2] = up2(uq0.z) * s2; q2[3] = up2(uq0.w) * s2;
    q2[4] = up2(uq1.x) * s2; q2[5] = up2(uq1.y) * s2;
    q2[6] = up2(uq1.z) * s2; q2[7] = up2(uq1.w) * s2;
  }
  __syncthreads();

  // ---- scores: 9 taps, 2 planes each (this half), branch-free ----
  const int p0 = 2 * half, p1 = 2 * half + 1;
  float sc[9];
#pragma unroll
  for (int i = 0; i < 3; ++i) {
#pragma unroll
    for (int j = 0; j < 3; ++j) {
      const int lp = (ph + i * d) * 22 + (pw + j * d);
      const uint4 k0 = *(const uint4*)&lds[(p0 * 485 + lp) * 8];
      const uint4 k1 = *(const uint4*)&lds[(p1 * 485 + lp) * 8];
      f32x2 a = q2[0] * up2(k0.x);
      a += q2[1] * up2(k0.y); a += q2[2] * up2(k0.z); a += q2[3] * up2(k0.w);
      a += q2[4] * up2(k1.x); a += q2[5] * up2(k1.y);
      a += q2[6] * up2(k1.z); a += q2[7] * up2(k1.w);
      sc[i * 3 + j] = a.x + a.y;        // half-dot
    }
  }
  // complete the 32-ch dot across the lane pair
#pragma unroll
  for (int k = 0; k < 9; ++k) sc[k] += __shfl_xor(sc[k], 1);

  // ---- softmax over 9 (identical in both halves) ----
  float mx = sc[0];
#pragma unroll
  for (int k = 1; k < 9; ++k) mx = fmaxf(mx, sc[k]);
  float sum = 0.f;
#pragma unroll
  for (int k = 0; k < 9; ++k) { sc[k] = __expf(sc[k] - mx); sum += sc[k]; }
  const float inv = 1.f / sum;

  // ---- all waves done reading K; overwrite buffer with V ----
  __syncthreads();
#pragma unroll
  for (int it = 0; it < 4; ++it) {
    const int px = it * 128 + t4;
    const int r = px / 22, c = px % 22;
    const int gh = h0 - d + r;
    const int gw = w0 - d + c;
    const bool ok = ((unsigned)gh < 128u) && ((unsigned)gw < 128u);
    const int hcl = min(max(gh, 0), 127);
    const int wcl = min(max(gw, 0), 127);
    const int gp = (((b << 7) | hcl) << 7) | wcl;
    uint4 u = *(const uint4*)(qkv + (size_t)gp * 768 + 512 + schoff);
    if (!ok) u = make_uint4(0u, 0u, 0u, 0u);
    if (it < 3 || t < 400) *(uint4*)&lds[(splane * 485 + px) * 8] = u;
  }
  __syncthreads();

  // ---- weighted V accumulate (this half's 16 ch), branch-free ----
  f32x2 o2[8];
#pragma unroll
  for (int k = 0; k < 8; ++k) o2[k] = (f32x2){0.f, 0.f};
#pragma unroll
  for (int i = 0; i < 3; ++i) {
#pragma unroll
    for (int j = 0; j < 3; ++j) {
      const int lp = (ph + i * d) * 22 + (pw + j * d);
      const uint4 v0 = *(const uint4*)&lds[(p0 * 485 + lp) * 8];
      const uint4 v1 = *(const uint4*)&lds[(p1 * 485 + lp) * 8];
      const float wv = sc[i * 3 + j] * inv;
      const f32x2 w2 = {wv, wv};
      o2[0] += w2 * up2(v0.x); o2[1] += w2 * up2(v0.y);
      o2[2] += w2 * up2(v0.z); o2[3] += w2 * up2(v0.w);
      o2[4] += w2 * up2(v1.x); o2[5] += w2 * up2(v1.y);
      o2[6] += w2 * up2(v1.z); o2[7] += w2 * up2(v1.w);
    }
  }

  // ---- store 16 ch bf16 ----
  unsigned short* op = xo + (size_t)gp0 * 256 + choff + half * 16;
  uint4 s0, s1;
  s0.x = pk2bf(o2[0].x, o2[0].y); s0.y = pk2bf(o2[1].x, o2[1].y);
  s0.z = pk2bf(o2[2].x, o2[2].y); s0.w = pk2bf(o2[3].x, o2[3].y);
  s1.x = pk2bf(o2[4].x, o2[4].y); s1.y = pk2bf(o2[5].x, o2[5].y);
  s1.z = pk2bf(o2[6].x, o2[6].y); s1.w = pk2bf(o2[7].x, o2[7].y);
  *(uint4*)op       = s0;
  *(uint4*)(op + 8) = s1;
}

// ---------------------------------------------------------------------------
extern "C" void kernel_launch(void* const* d_in, const int* in_sizes, int n_in,
                              void* d_out, int out_size, void* d_ws, size_t ws_size,
                              hipStream_t stream) {
  const float* x     = (const float*)d_in[0];
  const float* Wqkv  = (const float*)d_in[1];
  const float* Wproj = (const float*)d_in[2];
  const float* bproj = (const float*)d_in[3];

  const int M = 4 * 128 * 128;   // 65536 pixels
  const int C = 256;

  // workspace layout (bf16 ushorts): qkv | xo | Wqkv_b | Wproj_b (~130 MB)
  unsigned short* qkvb   = (unsigned short*)d_ws;
  unsigned short* xob    = qkvb + (size_t)M * 3 * C;
  unsigned short* wqkvb  = xob + (size_t)M * C;

  // both weight matrices: (3*C*C + C*C)/8 / 256 = 128 blocks, dsts contiguous
  cvt_w_both<<<128, 256, 0, stream>>>(Wqkv, Wproj, wqkvb);

  // QKV GEMM reads x directly as f32 (cvt fused at fragment load)
  gemm_bt<0, 1><<<(M / 128) * (3 * C / 128), 256, 0, stream>>>(
      (const void*)x, wqkvb, (void*)qkvb, nullptr, 3 * C, 3 * C / 128);

  // 4 batches x 8x8 tiles x 8 combos = 2048 blocks, 512 threads (px x half)
  attn_kernel<<<2048, 512, 0, stream>>>(qkvb, xob);

  gemm_bt<1, 0><<<(M / 128) * (C / 128), 256, 0, stream>>>(
      (const void*)xob, wqkvb + (size_t)3 * C * C, d_out, bproj, C, C / 128);
}